// Round 20
// baseline (184.209 us; speedup 1.0000x reference)
//
#include <hip/hip_runtime.h>
#include <hip/hip_bf16.h>
#include <math.h>

// ---------------------------------------------------------------------------
// CrossModalAttention on MI355X (gfx950)
//   B=4, Cu=320, Cj=1024, H=W=64 (N=4096), ATTN_DIM=256, scale = 1/16
// Round 20: V prefetched one iteration ahead in the PV role (persistent
// vfA/vfB regs; VLOAD(i) issued after PV_COMPUTE(i-1), before STAGE K[i+2]).
// vmcnt(14) leaves VLOAD(i)+STAGE(i+2) in flight while draining STAGE(i+1)
// (same K guarantee as R19). Everything else identical to R19.
// ---------------------------------------------------------------------------

typedef unsigned short u16;
typedef __attribute__((ext_vector_type(8))) short bf16x8;
typedef __attribute__((ext_vector_type(4))) float f32x4;
typedef __attribute__((ext_vector_type(16))) float f32x16;
typedef __attribute__((ext_vector_type(4))) unsigned short u16x4;

#define NB 4
#define CU 320
#define CJ 1024
#define NN 4096
#define AD 256

// ws layout (bytes)
#define XU_OFF 0u
#define XJ_OFF 10485760u
#define QB_OFF 44040192u
#define KB_OFF 52428800u
#define VB_OFF 60817408u
#define WQ_OFF 71303168u
#define WK_OFF 71467008u
#define WV_OFF 71991296u
#define WO_OFF 72646656u
#define AO_OFF XU_OFF

__device__ __forceinline__ u16 f2b(float f) {
    union { float f; unsigned u; } v; v.f = f;
    unsigned u = v.u;
    unsigned r = (u + 0x7fffu + ((u >> 16) & 1u)) >> 16;
    return (u16)r;
}

__device__ __forceinline__ float b2f(u16 x) {
    union { unsigned u; float f; } v; v.u = ((unsigned)x) << 16;
    return v.f;
}

__device__ __forceinline__ unsigned cvt_pk_bf16(float lo, float hi) {
    unsigned r;
    asm("v_cvt_pk_bf16_f32 %0, %1, %2" : "=v"(r) : "v"(lo), "v"(hi));
    return r;
}

__device__ __forceinline__ float exp2_fast(float x) {
    float r;
    asm("v_exp_f32 %0, %1" : "=v"(r) : "v"(x));
    return r;
}

__device__ __forceinline__ void async_cp16(const u16* g, char* l) {
    __builtin_amdgcn_global_load_lds(
        (const __attribute__((address_space(1))) unsigned int*)g,
        (__attribute__((address_space(3))) unsigned int*)l, 16, 0, 0);
}

// ---------------- fused prep: transpose unet, transpose janus, weight cast ----
__global__ __launch_bounds__(256) void prep_kernel(
        const float* __restrict__ unet, const float* __restrict__ janus,
        const float* __restrict__ Wq, const float* __restrict__ Wk,
        const float* __restrict__ Wv, const float* __restrict__ Wo,
        u16* __restrict__ Xu, u16* __restrict__ Xj,
        u16* __restrict__ wq, u16* __restrict__ wk,
        u16* __restrict__ wv, u16* __restrict__ wo) {
    __shared__ float tile[64][65];
    int bid = blockIdx.x;
    int t = threadIdx.x;

    if (bid < 5376) {
        const float* src;
        u16* dst;
        int C, x, y, z;
        if (bid < 1280) {
            z = bid / 320; int rem = bid % 320; y = rem / 64; x = rem % 64;
            C = CU; src = unet + (size_t)z * CU * NN; dst = Xu + (size_t)z * NN * CU;
        } else {
            int idx = bid - 1280;
            z = idx / 1024; int rem = idx % 1024; y = rem / 64; x = rem % 64;
            C = CJ; src = janus + (size_t)z * CJ * NN; dst = Xj + (size_t)z * NN * CJ;
        }
        int n0 = x * 64, c0 = y * 64;
        int nl = t & 63, cl = t >> 6;
        #pragma unroll
        for (int k = 0; k < 16; ++k) {
            int c = cl + k * 4;
            tile[c][nl] = src[(size_t)(c0 + c) * NN + n0 + nl];
        }
        __syncthreads();
        int cl2 = t & 63, nl2 = t >> 6;
        #pragma unroll
        for (int k = 0; k < 16; ++k) {
            int n = nl2 + k * 4;
            dst[(size_t)(n0 + n) * C + c0 + cl2] = f2b(tile[cl2][n]);
        }
        return;
    }
    int id = (bid - 5376) * 256 + t;
    if (id < 81920) { wq[id] = f2b(Wq[id]); return; }
    id -= 81920;
    if (id < 262144) { wk[id] = f2b(Wk[id]); return; }
    id -= 262144;
    if (id < 327680) { wv[id] = f2b(Wv[id]); return; }
    id -= 327680;
    if (id < 102400) { wo[id] = f2b(Wo[id]); }
}

// ---------------- unified GEMM: out = A(16384xKD) @ W(NOUTxKD)^T ----------------
// 256x64 tile, BK=64, 8 waves (wr4 x wc2, 64x32 each), 2 blocks/CU.
template <int EPI, int KD, int NOUT>
__global__ __launch_bounds__(512, 4) void gemm_kernel(
        const u16* __restrict__ A, const u16* __restrict__ W,
        const float* __restrict__ bias, void* __restrict__ outp,
        const float* __restrict__ unet, float alpha) {
    __shared__ __align__(16) char smem[81920];
    const int t = threadIdx.x;
    const int lane = t & 63, wave = t >> 6;
    const int r = lane & 15, h = lane >> 4;
    const int wr = wave >> 1, wc = wave & 1;
    const int m0 = blockIdx.x * 256;
    const int bn0 = blockIdx.y * 64;

    int goffA[4], goffB;
    #pragma unroll
    for (int n = 0; n < 4; ++n) {
        int c = n * 512 + t;
        int row = c >> 3, s = c & 7;
        goffA[n] = (m0 + row) * KD + ((s ^ (row & 7)) << 3);
    }
    {
        int row = t >> 3, s = t & 7;
        goffB = (bn0 + row) * KD + ((s ^ (row & 7)) << 3);
    }
    const unsigned wb = (unsigned)(t & ~63) * 16u;

    #define GSTAGE(BUF, KT) do {                                                  \
        _Pragma("unroll")                                                         \
        for (int n_ = 0; n_ < 4; ++n_)                                            \
            async_cp16(A + goffA[n_] + (KT) * 64,                                 \
                       smem + (BUF) * 40960 + n_ * 8192 + wb);                    \
        async_cp16(W + goffB + (KT) * 64,                                         \
                   smem + (BUF) * 40960 + 32768 + wb);                            \
    } while (0)

    f32x4 acc[4][2];
    #pragma unroll
    for (int fr = 0; fr < 4; ++fr)
        #pragma unroll
        for (int fc = 0; fc < 2; ++fc) acc[fr][fc] = (f32x4)0.0f;

    GSTAGE(0, 0);
    int buf = 0;
    const int KS = KD / 64;
    for (int kt = 0; kt < KS; ++kt) {
        if (kt < KS - 1) {
            GSTAGE(buf ^ 1, kt + 1);
            asm volatile("s_waitcnt vmcnt(5)" ::: "memory");
        } else {
            asm volatile("s_waitcnt vmcnt(0)" ::: "memory");
        }
        __builtin_amdgcn_s_barrier();
        asm volatile("" ::: "memory");
        const char* Ab = smem + buf * 40960;
        const char* Bb = smem + buf * 40960 + 32768;
        #pragma unroll
        for (int kk = 0; kk < 2; ++kk) {
            bf16x8 af[4], bf[2];
            #pragma unroll
            for (int fr = 0; fr < 4; ++fr) {
                int row = wr * 64 + fr * 16 + r;
                af[fr] = *(const bf16x8*)(Ab + row * 128 + (((kk * 4 + h) ^ (row & 7)) << 4));
            }
            #pragma unroll
            for (int fc = 0; fc < 2; ++fc) {
                int rowb = wc * 32 + fc * 16 + r;
                bf[fc] = *(const bf16x8*)(Bb + rowb * 128 + (((kk * 4 + h) ^ (rowb & 7)) << 4));
            }
            #pragma unroll
            for (int fr = 0; fr < 4; ++fr)
                #pragma unroll
                for (int fc = 0; fc < 2; ++fc)
                    acc[fr][fc] = __builtin_amdgcn_mfma_f32_16x16x32_bf16(
                        af[fr], bf[fc], acc[fr][fc], 0, 0, 0);
        }
        asm volatile("" ::: "memory");
        __builtin_amdgcn_s_barrier();
        asm volatile("" ::: "memory");
        buf ^= 1;
    }
    #undef GSTAGE

    const int mw = m0 + wr * 64;
    const int ob0 = bn0 + wc * 32;

    if (EPI == 0) {
        u16* out = (u16*)outp;
        #pragma unroll
        for (int fc = 0; fc < 2; ++fc) {
            int o = ob0 + fc * 16 + r;
            float bs = bias[o];
            #pragma unroll
            for (int fr = 0; fr < 4; ++fr)
                #pragma unroll
                for (int rr = 0; rr < 4; ++rr) {
                    int mrow = mw + fr * 16 + h * 4 + rr;
                    out[(size_t)mrow * NOUT + o] = f2b((acc[fr][fc][rr] + bs) * alpha);
                }
        }
    } else {
        float* tile = (float*)(smem + wave * 8704);   // [32][68] f32
        #pragma unroll
        for (int fc = 0; fc < 2; ++fc)
            #pragma unroll
            for (int fr = 0; fr < 4; ++fr)
                *(f32x4*)(tile + (fc * 16 + r) * 68 + fr * 16 + h * 4) = acc[fr][fc];
        __builtin_amdgcn_s_waitcnt(0);
        float* out = (float*)outp;
        int bb = mw >> 12, nb = mw & 4095;
        #pragma unroll
        for (int g = 0; g < 8; ++g) {
            int chunk = g * 64 + lane;
            int row = chunk >> 4, ns = chunk & 15;
            int o = ob0 + row;
            size_t base = (size_t)bb * CU * NN + (size_t)o * NN + nb + ns * 4;
            f32x4 v = *(const f32x4*)(tile + row * 68 + ns * 4);
            f32x4 u = *(const f32x4*)(unet + base);
            float bs = bias[o];
            f32x4 res;
            #pragma unroll
            for (int rr = 0; rr < 4; ++rr) res[rr] = v[rr] + bs + u[rr];
            *(f32x4*)(out + base) = res;
        }
    }
}

// ---------------- fused K+V projection (KD=1024, 256x64 tile) ----------------
__global__ __launch_bounds__(512, 4) void gemm_kv_kernel(
        const u16* __restrict__ A, const u16* __restrict__ Wk,
        const u16* __restrict__ Wv, const float* __restrict__ bk,
        const float* __restrict__ bv, u16* __restrict__ Kb,
        u16* __restrict__ Vb) {
    const int KD = 1024;
    __shared__ __align__(16) char smem[81920];
    const int t = threadIdx.x;
    const int lane = t & 63, wave = t >> 6;
    const int r = lane & 15, h = lane >> 4;
    const int wr = wave >> 1, wc = wave & 1;
    const int m0 = blockIdx.x * 256;
    const bool isK = blockIdx.y < 4;
    const int bn0 = (isK ? blockIdx.y : (blockIdx.y - 4)) * 64;
    const u16* W = isK ? Wk : Wv;
    const float* bias = isK ? bk : bv;

    int goffA[4], goffB;
    #pragma unroll
    for (int n = 0; n < 4; ++n) {
        int c = n * 512 + t;
        int row = c >> 3, s = c & 7;
        goffA[n] = (m0 + row) * KD + ((s ^ (row & 7)) << 3);
    }
    {
        int row = t >> 3, s = t & 7;
        goffB = (bn0 + row) * KD + ((s ^ (row & 7)) << 3);
    }
    const unsigned wb = (unsigned)(t & ~63) * 16u;

    #define GSTAGE(BUF, KT) do {                                                  \
        _Pragma("unroll")                                                         \
        for (int n_ = 0; n_ < 4; ++n_)                                            \
            async_cp16(A + goffA[n_] + (KT) * 64,                                 \
                       smem + (BUF) * 40960 + n_ * 8192 + wb);                    \
        async_cp16(W + goffB + (KT) * 64,                                         \
                   smem + (BUF) * 40960 + 32768 + wb);                            \
    } while (0)

    f32x4 acc[4][2];
    #pragma unroll
    for (int fr = 0; fr < 4; ++fr)
        #pragma unroll
        for (int fc = 0; fc < 2; ++fc) acc[fr][fc] = (f32x4)0.0f;

    GSTAGE(0, 0);
    int buf = 0;
    for (int kt = 0; kt < 16; ++kt) {
        if (kt < 15) {
            GSTAGE(buf ^ 1, kt + 1);
            asm volatile("s_waitcnt vmcnt(5)" ::: "memory");
        } else {
            asm volatile("s_waitcnt vmcnt(0)" ::: "memory");
        }
        __builtin_amdgcn_s_barrier();
        asm volatile("" ::: "memory");
        const char* Ab = smem + buf * 40960;
        const char* Bb = smem + buf * 40960 + 32768;
        #pragma unroll
        for (int kk = 0; kk < 2; ++kk) {
            bf16x8 af[4], bf[2];
            #pragma unroll
            for (int fr = 0; fr < 4; ++fr) {
                int row = wr * 64 + fr * 16 + r;
                af[fr] = *(const bf16x8*)(Ab + row * 128 + (((kk * 4 + h) ^ (row & 7)) << 4));
            }
            #pragma unroll
            for (int fc = 0; fc < 2; ++fc) {
                int rowb = wc * 32 + fc * 16 + r;
                bf[fc] = *(const bf16x8*)(Bb + rowb * 128 + (((kk * 4 + h) ^ (rowb & 7)) << 4));
            }
            #pragma unroll
            for (int fr = 0; fr < 4; ++fr)
                #pragma unroll
                for (int fc = 0; fc < 2; ++fc)
                    acc[fr][fc] = __builtin_amdgcn_mfma_f32_16x16x32_bf16(
                        af[fr], bf[fc], acc[fr][fc], 0, 0, 0);
        }
        asm volatile("" ::: "memory");
        __builtin_amdgcn_s_barrier();
        asm volatile("" ::: "memory");
        buf ^= 1;
    }
    #undef GSTAGE

    const int mw = m0 + wr * 64;
    const int ob0 = bn0 + wc * 32;

    if (isK) {
        #pragma unroll
        for (int fc = 0; fc < 2; ++fc) {
            int o = ob0 + fc * 16 + r;
            float bs = bias[o];
            #pragma unroll
            for (int fr = 0; fr < 4; ++fr)
                #pragma unroll
                for (int rr = 0; rr < 4; ++rr) {
                    int mrow = mw + fr * 16 + h * 4 + rr;
                    Kb[(size_t)mrow * AD + o] = f2b((acc[fr][fc][rr] + bs));
                }
        }
    } else {
        u16* tile = (u16*)(smem + wave * 4608);
        #pragma unroll
        for (int fc = 0; fc < 2; ++fc) {
            int o = ob0 + fc * 16 + r;
            float bs = bias[o];
            #pragma unroll
            for (int fr = 0; fr < 4; ++fr) {
                u16x4 v4;
                #pragma unroll
                for (int rr = 0; rr < 4; ++rr) v4[rr] = f2b(acc[fr][fc][rr] + bs);
                *(u16x4*)(tile + (fc * 16 + r) * 72 + fr * 16 + h * 4) = v4;
            }
        }
        __builtin_amdgcn_s_waitcnt(0);
        int bb = mw >> 12, nb = mw & 4095;
        #pragma unroll
        for (int g = 0; g < 4; ++g) {
            int chunk = g * 64 + lane;
            int row = chunk >> 3, ns = chunk & 7;
            int ch = ob0 + row;
            int j = nb + ns * 8;
            bf16x8 val = *(const bf16x8*)(tile + row * 72 + ns * 8);
            size_t off = (size_t)bb * CU * NN + (size_t)(ch >> 5) * (NN * 32)
                       + (size_t)(j >> 4) * 512
                       + (size_t)((ch & 31) + ((j >> 3) & 1) * 32) * 8 + (j & 7);
            *(bf16x8*)(Vb + off) = val;
        }
    }
}

// ---------------- flash attention (round-20: V prefetch + 3-deep K) ---------
// 256 blocks x 768 thr (12 waves): waves 0-3 = QK (iw = w>>1, jw = w&1),
// waves 4-11 = PV (iw = pvid>>2, pj = (pvid>>1)&1, cgh = pvid&1, o[5]).
// LDS 117,248 B: kbuf 3x32K @0; pbuf 2 par x 8960 @98304; ml @116224.
// PV body: PV_COMPUTE(i-1) on prefetched vf regs -> VLOAD(i) -> STAGE K[i+2]
// -> vmcnt(14) (drains STAGE(i+1); leaves VLOAD(i)+STAGE(i+2) in flight).
__global__ __launch_bounds__(768, 3) void attn_kernel(
        const u16* __restrict__ Q, const u16* __restrict__ K,
        const u16* __restrict__ V, u16* __restrict__ AO) {
    __shared__ __align__(16) char smem[117248];

    const int t = threadIdx.x;
    const int lane = t & 63;
    const int wave = t >> 6;          // 0..11
    const int r = lane & 31, hi = lane >> 5;

    int linear = blockIdx.x;
    int swz = (linear & 7) * 32 + (linear >> 3);
    int b = swz >> 6;
    int i0 = (swz & 63) * 64;

    const u16* Qb = Q + ((size_t)b * NN + i0) * AD;
    const u16* Kb = K + (size_t)b * NN * AD;
    const u16* Vb = V + (size_t)b * CU * NN;

    // ---- prologue: stage K[0] AND K[1] (4096 chunks) with all 768 threads ----
    {
        #pragma unroll
        for (int n = 0; n < 5; ++n) {
            int id = n * 768 + t;
            if (id < 4096) {
                int tile = id >> 11;
                int idx = id & 2047;
                int row = idx >> 5, c16 = idx & 31;
                async_cp16(Kb + tile * 16384 + row * 256 + ((c16 ^ (row & 31)) << 3),
                           smem + (unsigned)(n * 768 + (t & ~63)) * 16u);
            }
        }
        if (t < 256) {
            int id = 3840 + t;
            int tile = id >> 11;
            int idx = id & 2047;
            int row = idx >> 5, c16 = idx & 31;
            async_cp16(Kb + tile * 16384 + row * 256 + ((c16 ^ (row & 31)) << 3),
                       smem + (unsigned)(3840 + (t & ~63)) * 16u);
        }
    }
    asm volatile("s_waitcnt vmcnt(0)" ::: "memory");
    __builtin_amdgcn_s_barrier();     // K[0], K[1] ready
    asm volatile("" ::: "memory");

    if (wave < 4) {
        // ================= QK role =================
        const int iw = wave >> 1;
        const int jw = wave & 1;
        bf16x8 q[16];
        #pragma unroll
        for (int kk = 0; kk < 16; ++kk)
            q[kk] = *(const bf16x8*)(Qb + (size_t)(iw * 32 + r) * AD + kk * 16 + hi * 8);
        float m = -INFINITY, lsum = 0.0f;

        for (int i = 0; i < 64; ++i) {
            if (i) {
                __builtin_amdgcn_s_barrier();
                asm volatile("" ::: "memory");
            }
            const char* Kt = smem + (i % 3) * 32768 + jw * 16384;
            f32x16 sa = (f32x16)0.0f, sb = (f32x16)0.0f;
            __builtin_amdgcn_s_setprio(1);
            #pragma unroll
            for (int kk = 0; kk < 8; ++kk) {
                bf16x8 k0 = *(const bf16x8*)(Kt + r * 512 + (((2 * kk + hi) ^ r) << 4));
                bf16x8 k1 = *(const bf16x8*)(Kt + r * 512 + (((2 * (kk + 8) + hi) ^ r) << 4));
                sa = __builtin_amdgcn_mfma_f32_32x32x16_bf16(k0, q[kk], sa, 0, 0, 0);
                sb = __builtin_amdgcn_mfma_f32_32x32x16_bf16(k1, q[kk + 8], sb, 0, 0, 0);
            }
            __builtin_amdgcn_s_setprio(0);
            f32x16 s = sa + sb;

            float x0 = fmaxf(s[0], s[1]),   x1 = fmaxf(s[2], s[3]);
            float x2 = fmaxf(s[4], s[5]),   x3 = fmaxf(s[6], s[7]);
            float x4 = fmaxf(s[8], s[9]),   x5 = fmaxf(s[10], s[11]);
            float x6 = fmaxf(s[12], s[13]), x7 = fmaxf(s[14], s[15]);
            float pmax = fmaxf(fmaxf(fmaxf(x0, x1), fmaxf(x2, x3)),
                               fmaxf(fmaxf(x4, x5), fmaxf(x6, x7)));
            pmax = fmaxf(pmax, __shfl_xor(pmax, 32));
            char* pb = smem + 98304 + (i & 1) * 8960;
            int fl = __any(pmax > m + 8.0f) ? 1 : 0;
            if (fl) {
                float mn = fmaxf(m, pmax);
                float al = exp2_fast(m - mn);
                m = mn;
                lsum *= al;
                if (lane < 32) *(float*)(pb + 8192 + (iw * 2 + jw) * 128 + r * 4) = al;
            }
            if (lane == 0) *(int*)(pb + 8704 + (iw * 2 + jw) * 4) = fl;
            float p[16];
            #pragma unroll
            for (int e = 0; e < 16; ++e) p[e] = exp2_fast(s[e] - m);
            float y0 = (p[0] + p[1]) + (p[2] + p[3]);
            float y1 = (p[4] + p[5]) + (p[6] + p[7]);
            float y2 = (p[8] + p[9]) + (p[10] + p[11]);
            float y3 = (p[12] + p[13]) + (p[14] + p[15]);
            float ps = (y0 + y1) + (y2 + y3);
            ps += __shfl_xor(ps, 32);
            lsum += ps;

            #pragma unroll
            for (int ks = 0; ks < 2; ++ks) {
                unsigned a0 = cvt_pk_bf16(p[8 * ks + 0], p[8 * ks + 1]);
                unsigned a1 = cvt_pk_bf16(p[8 * ks + 2], p[8 * ks + 3]);
                unsigned b0 = cvt_pk_bf16(p[8 * ks + 4], p[8 * ks + 5]);
                unsigned b1 = cvt_pk_bf16(p[8 * ks + 6], p[8 * ks + 7]);
                asm("v_permlane32_swap_b32 %0, %1" : "+v"(a0), "+v"(b0));
                asm("v_permlane32_swap_b32 %0, %1" : "+v"(a1), "+v"(b1));
                union { unsigned w[4]; bf16x8 v; } u;
                u.w[0] = a0; u.w[1] = a1; u.w[2] = b0; u.w[3] = b1;
                *(bf16x8*)(pb + (iw * 2 + jw) * 2048 + ks * 1024 + lane * 16) = u.v;
            }
            asm volatile("s_waitcnt lgkmcnt(0)" ::: "memory");
            __builtin_amdgcn_sched_barrier(0);
        }
        __builtin_amdgcn_s_barrier();   // P(63) published
        asm volatile("" ::: "memory");
        if (lane < 32) {
            *(float*)(smem + 116224 + (iw * 2 + jw) * 128 + r * 4) = m;
            *(float*)(smem + 116224 + 512 + (iw * 2 + jw) * 128 + r * 4) = lsum;
        }
        __syncthreads();    // syncA
        __syncthreads();    // syncB
        __syncthreads();    // syncC
    } else {
        // ================= PV role =================
        const int pvid = wave - 4;          // 0..7
        const int iw = pvid >> 2;           // 32-row group
        const int pj = (pvid >> 1) & 1;     // which jw's P
        const int cgh = pvid & 1;           // 160-ch half
        const int tp = t - 256;             // 0..511 over waves 4-11

        int goffp[4];
        #pragma unroll
        for (int n = 0; n < 4; ++n) {
            int id = n * 512 + tp;
            int row = (id >> 5) & 63;
            int c16 = id & 31;
            goffp[n] = row * 256 + ((c16 ^ (row & 31)) << 3);
        }
        const unsigned wbp = (unsigned)(tp & ~63) * 16u;

        #define STAGE(BUF, KP) do {                                               \
            _Pragma("unroll")                                                     \
            for (int n_ = 0; n_ < 4; ++n_)                                        \
                async_cp16((KP) + goffp[n_],                                      \
                           smem + (BUF) * 32768 + n_ * 8192 + wbp);               \
        } while (0)

        f32x16 o[5];
        #pragma unroll
        for (int ct = 0; ct < 5; ++ct) o[ct] = (f32x16)0.0f;
        const u16* vb = Vb + (size_t)(cgh * 5) * 131072 + lane * 8;

        bf16x8 vfA[5], vfB[5];

        #define VLOAD(TI) do {                                                    \
            _Pragma("unroll")                                                     \
            for (int c = 0; c < 5; ++c)                                           \
                vfA[c] = *(const bf16x8*)(vb + (size_t)c * 131072 +               \
                                          ((TI) * 4 + pj * 2 + 0) * 512);         \
            _Pragma("unroll")                                                     \
            for (int c = 0; c < 5; ++c)                                           \
                vfB[c] = *(const bf16x8*)(vb + (size_t)c * 131072 +               \
                                          ((TI) * 4 + pj * 2 + 1) * 512);         \
        } while (0)

        #define PV_COMPUTE(TI) do {                                               \
            const char* pb = smem + 98304 + ((TI) & 1) * 8960;                    \
            int fl = *(volatile const int*)(pb + 8704 + (iw * 2 + pj) * 4);       \
            bf16x8 pf0 = *(const bf16x8*)(pb + (iw * 2 + pj) * 2048 + lane * 16); \
            bf16x8 pf1 = *(const bf16x8*)(pb + (iw * 2 + pj) * 2048 + 1024 +      \
                                          lane * 16);                             \
            if (fl) {                                                             \
                float alv = *(volatile const float*)(pb + 8192 +                  \
                                (iw * 2 + pj) * 128 + (lane & 31) * 4);           \
                _Pragma("unroll")                                                 \
                for (int ct = 0; ct < 5; ++ct) o[ct] *= alv;                      \
            }                                                                     \
            __builtin_amdgcn_s_setprio(1);                                        \
            _Pragma("unroll")                                                     \
            for (int ct = 0; ct < 5; ++ct)                                        \
                o[ct] = __builtin_amdgcn_mfma_f32_32x32x16_bf16(vfA[ct], pf0,     \
                                                                o[ct], 0, 0, 0); \
            _Pragma("unroll")                                                     \
            for (int ct = 0; ct < 5; ++ct)                                        \
                o[ct] = __builtin_amdgcn_mfma_f32_32x32x16_bf16(vfB[ct], pf1,     \
                                                                o[ct], 0, 0, 0); \
            __builtin_amdgcn_s_setprio(0);                                        \
        } while (0)

        for (int i = 0; i < 64; ++i) {
            if (i) {
                __builtin_amdgcn_s_barrier();
                asm volatile("" ::: "memory");
            }
            if (i >= 1) PV_COMPUTE(i - 1);
            VLOAD(i);
            if (i <= 61) {
                STAGE((i + 2) % 3, Kb + (i + 2) * 16384);
                asm volatile("s_waitcnt vmcnt(14)" ::: "memory");
            } else {
                asm volatile("s_waitcnt vmcnt(10)" ::: "memory");
            }
        }
        __builtin_amdgcn_s_barrier();   // P(63) published
        asm volatile("" ::: "memory");
        PV_COMPUTE(63);

        __syncthreads();    // syncA: m/l published, kbuf dead
        float m0 = *(const float*)(smem + 116224 + (iw * 2 + pj) * 128 + r * 4);
        float l0 = *(const float*)(smem + 116224 + 512 + (iw * 2 + pj) * 128 + r * 4);
        float m1 = *(const float*)(smem + 116224 + (iw * 2 + (pj ^ 1)) * 128 + r * 4);
        float l1 = *(const float*)(smem + 116224 + 512 + (iw * 2 + (pj ^ 1)) * 128 + r * 4);
        float M = fmaxf(m0, m1);
        float fsc = exp2_fast(m0 - M);
        float fo = exp2_fast(m1 - M);
        float inv = 1.0f / (l0 * fsc + l1 * fo);

        u16* fb = (u16*)smem;              // [64][328] bf16, in-place merge
        if (pj == 1) {
            #pragma unroll
            for (int ct = 0; ct < 5; ++ct)
                #pragma unroll
                for (int e = 0; e < 16; ++e) {
                    int c = cgh * 160 + ct * 32 + (e & 3) + 8 * (e >> 2) + 4 * hi;
                    fb[(iw * 32 + r) * 328 + c] = f2b(o[ct][e] * fsc);
                }
        }
        __syncthreads();    // syncB
        if (pj == 0) {
            #pragma unroll
            for (int ct = 0; ct < 5; ++ct)
                #pragma unroll
                for (int g = 0; g < 4; ++g) {
                    int cb = cgh * 160 + ct * 32 + 8 * g + 4 * hi;
                    u16* fr = &fb[(iw * 32 + r) * 328 + cb];
                    float v0 = (o[ct][4 * g + 0] * fsc + b2f(fr[0])) * inv;
                    float v1 = (o[ct][4 * g + 1] * fsc + b2f(fr[1])) * inv;
                    float v2 = (o[ct][4 * g + 2] * fsc + b2f(fr[2])) * inv;
                    float v3 = (o[ct][4 * g + 3] * fsc + b2f(fr[3])) * inv;
                    *(unsigned*)(fr) = cvt_pk_bf16(v0, v1);
                    *(unsigned*)(fr + 2) = cvt_pk_bf16(v2, v3);
                }
        }
        __syncthreads();    // syncC
        #undef PV_COMPUTE
        #undef VLOAD
        #undef STAGE
    }

    // ---- common: store AO (64 q-rows x 320 ch) from smem [64][328] ----
    const u16* ob = (const u16*)smem;
    u16* AOb = AO + ((size_t)b * NN + i0) * CU;
    #pragma unroll
    for (int n = 0; n < 3; ++n) {
        int id = n * 768 + t;
        int row = id / 40, c8 = id % 40;
        bf16x8 val = *(const bf16x8*)(ob + row * 328 + c8 * 8);
        *(bf16x8*)(AOb + (size_t)row * CU + c8 * 8) = val;
    }
    if (t < 256) {
        int id = 2304 + t;
        int row = id / 40, c8 = id % 40;
        bf16x8 val = *(const bf16x8*)(ob + row * 328 + c8 * 8);
        *(bf16x8*)(AOb + (size_t)row * CU + c8 * 8) = val;
    }
}

extern "C" void kernel_launch(void* const* d_in, const int* in_sizes, int n_in,
                              void* d_out, int out_size, void* d_ws, size_t ws_size,
                              hipStream_t stream) {
    const float* unet  = (const float*)d_in[0];
    const float* janus = (const float*)d_in[1];
    const float* Wq = (const float*)d_in[2];
    const float* bq = (const float*)d_in[3];
    const float* Wk = (const float*)d_in[4];
    const float* bk = (const float*)d_in[5];
    const float* Wv = (const float*)d_in[6];
    const float* bv = (const float*)d_in[7];
    const float* Wo = (const float*)d_in[8];
    const float* bo = (const float*)d_in[9];
    float* out = (float*)d_out;

    char* ws = (char*)d_ws;
    u16* Xu  = (u16*)(ws + XU_OFF);
    u16* Xj  = (u16*)(ws + XJ_OFF);
    u16* Qb  = (u16*)(ws + QB_OFF);
    u16* Kb  = (u16*)(ws + KB_OFF);
    u16* Vb  = (u16*)(ws + VB_OFF);
    u16* wq  = (u16*)(ws + WQ_OFF);
    u16* wk  = (u16*)(ws + WK_OFF);
    u16* wv  = (u16*)(ws + WV_OFF);
    u16* wo  = (u16*)(ws + WO_OFF);
    u16* AO  = (u16*)(ws + AO_OFF);

    // fused prep: transposes + weight cast
    prep_kernel<<<8400, 256, 0, stream>>>(unet, janus, Wq, Wk, Wv, Wo,
                                          Xu, Xj, wq, wk, wv, wo);

    // Q pre-scaled by (1/16) * log2(e) so softmax runs in exp2 domain
    gemm_kernel<0, 320, 256><<<dim3(64, 4), 512, 0, stream>>>(
        Xu, wq, bq, Qb, nullptr, 0.0901684411f);

    // fused K + V projections
    gemm_kv_kernel<<<dim3(64, 9), 512, 0, stream>>>(
        Xj, wk, wv, bk, bv, Kb, Vb);

    attn_kernel<<<256, 768, 0, stream>>>(Qb, Kb, Vb, AO);

    gemm_kernel<2, 320, 320><<<dim3(64, 5), 512, 0, stream>>>(
        AO, wo, bo, out, unet, 1.0f);
}

// Round 21
// 172.197 us; speedup vs baseline: 1.0698x; 1.0698x over previous
//
#include <hip/hip_runtime.h>
#include <hip/hip_bf16.h>
#include <math.h>

// ---------------------------------------------------------------------------
// CrossModalAttention on MI355X (gfx950)
//   B=4, Cu=320, Cj=1024, H=W=64 (N=4096), ATTN_DIM=256, scale = 1/16
// Round 21: revert to R19 (measured best, 172.7us total / 100us attn).
// attn: 3-deep K pipeline staged by PV waves, 4 QK + 8 PV wave roles,
// 64-row i-tiles, exp2-domain softmax, fragment-ordered V, in-place merge.
// GEMMs: 256x64 tiles, 512 thr, 2 blocks/CU. Prep fused.
// ---------------------------------------------------------------------------

typedef unsigned short u16;
typedef __attribute__((ext_vector_type(8))) short bf16x8;
typedef __attribute__((ext_vector_type(4))) float f32x4;
typedef __attribute__((ext_vector_type(16))) float f32x16;
typedef __attribute__((ext_vector_type(4))) unsigned short u16x4;

#define NB 4
#define CU 320
#define CJ 1024
#define NN 4096
#define AD 256

// ws layout (bytes)
#define XU_OFF 0u
#define XJ_OFF 10485760u
#define QB_OFF 44040192u
#define KB_OFF 52428800u
#define VB_OFF 60817408u
#define WQ_OFF 71303168u
#define WK_OFF 71467008u
#define WV_OFF 71991296u
#define WO_OFF 72646656u
#define AO_OFF XU_OFF

__device__ __forceinline__ u16 f2b(float f) {
    union { float f; unsigned u; } v; v.f = f;
    unsigned u = v.u;
    unsigned r = (u + 0x7fffu + ((u >> 16) & 1u)) >> 16;
    return (u16)r;
}

__device__ __forceinline__ float b2f(u16 x) {
    union { unsigned u; float f; } v; v.u = ((unsigned)x) << 16;
    return v.f;
}

__device__ __forceinline__ unsigned cvt_pk_bf16(float lo, float hi) {
    unsigned r;
    asm("v_cvt_pk_bf16_f32 %0, %1, %2" : "=v"(r) : "v"(lo), "v"(hi));
    return r;
}

__device__ __forceinline__ float exp2_fast(float x) {
    float r;
    asm("v_exp_f32 %0, %1" : "=v"(r) : "v"(x));
    return r;
}

__device__ __forceinline__ void async_cp16(const u16* g, char* l) {
    __builtin_amdgcn_global_load_lds(
        (const __attribute__((address_space(1))) unsigned int*)g,
        (__attribute__((address_space(3))) unsigned int*)l, 16, 0, 0);
}

// ---------------- fused prep: transpose unet, transpose janus, weight cast ----
__global__ __launch_bounds__(256) void prep_kernel(
        const float* __restrict__ unet, const float* __restrict__ janus,
        const float* __restrict__ Wq, const float* __restrict__ Wk,
        const float* __restrict__ Wv, const float* __restrict__ Wo,
        u16* __restrict__ Xu, u16* __restrict__ Xj,
        u16* __restrict__ wq, u16* __restrict__ wk,
        u16* __restrict__ wv, u16* __restrict__ wo) {
    __shared__ float tile[64][65];
    int bid = blockIdx.x;
    int t = threadIdx.x;

    if (bid < 5376) {
        const float* src;
        u16* dst;
        int C, x, y, z;
        if (bid < 1280) {
            z = bid / 320; int rem = bid % 320; y = rem / 64; x = rem % 64;
            C = CU; src = unet + (size_t)z * CU * NN; dst = Xu + (size_t)z * NN * CU;
        } else {
            int idx = bid - 1280;
            z = idx / 1024; int rem = idx % 1024; y = rem / 64; x = rem % 64;
            C = CJ; src = janus + (size_t)z * CJ * NN; dst = Xj + (size_t)z * NN * CJ;
        }
        int n0 = x * 64, c0 = y * 64;
        int nl = t & 63, cl = t >> 6;
        #pragma unroll
        for (int k = 0; k < 16; ++k) {
            int c = cl + k * 4;
            tile[c][nl] = src[(size_t)(c0 + c) * NN + n0 + nl];
        }
        __syncthreads();
        int cl2 = t & 63, nl2 = t >> 6;
        #pragma unroll
        for (int k = 0; k < 16; ++k) {
            int n = nl2 + k * 4;
            dst[(size_t)(n0 + n) * C + c0 + cl2] = f2b(tile[cl2][n]);
        }
        return;
    }
    int id = (bid - 5376) * 256 + t;
    if (id < 81920) { wq[id] = f2b(Wq[id]); return; }
    id -= 81920;
    if (id < 262144) { wk[id] = f2b(Wk[id]); return; }
    id -= 262144;
    if (id < 327680) { wv[id] = f2b(Wv[id]); return; }
    id -= 327680;
    if (id < 102400) { wo[id] = f2b(Wo[id]); }
}

// ---------------- unified GEMM: out = A(16384xKD) @ W(NOUTxKD)^T ----------------
// 256x64 tile, BK=64, 8 waves (wr4 x wc2, 64x32 each), 2 blocks/CU.
template <int EPI, int KD, int NOUT>
__global__ __launch_bounds__(512, 4) void gemm_kernel(
        const u16* __restrict__ A, const u16* __restrict__ W,
        const float* __restrict__ bias, void* __restrict__ outp,
        const float* __restrict__ unet, float alpha) {
    __shared__ __align__(16) char smem[81920];
    const int t = threadIdx.x;
    const int lane = t & 63, wave = t >> 6;
    const int r = lane & 15, h = lane >> 4;
    const int wr = wave >> 1, wc = wave & 1;
    const int m0 = blockIdx.x * 256;
    const int bn0 = blockIdx.y * 64;

    int goffA[4], goffB;
    #pragma unroll
    for (int n = 0; n < 4; ++n) {
        int c = n * 512 + t;
        int row = c >> 3, s = c & 7;
        goffA[n] = (m0 + row) * KD + ((s ^ (row & 7)) << 3);
    }
    {
        int row = t >> 3, s = t & 7;
        goffB = (bn0 + row) * KD + ((s ^ (row & 7)) << 3);
    }
    const unsigned wb = (unsigned)(t & ~63) * 16u;

    #define GSTAGE(BUF, KT) do {                                                  \
        _Pragma("unroll")                                                         \
        for (int n_ = 0; n_ < 4; ++n_)                                            \
            async_cp16(A + goffA[n_] + (KT) * 64,                                 \
                       smem + (BUF) * 40960 + n_ * 8192 + wb);                    \
        async_cp16(W + goffB + (KT) * 64,                                         \
                   smem + (BUF) * 40960 + 32768 + wb);                            \
    } while (0)

    f32x4 acc[4][2];
    #pragma unroll
    for (int fr = 0; fr < 4; ++fr)
        #pragma unroll
        for (int fc = 0; fc < 2; ++fc) acc[fr][fc] = (f32x4)0.0f;

    GSTAGE(0, 0);
    int buf = 0;
    const int KS = KD / 64;
    for (int kt = 0; kt < KS; ++kt) {
        if (kt < KS - 1) {
            GSTAGE(buf ^ 1, kt + 1);
            asm volatile("s_waitcnt vmcnt(5)" ::: "memory");
        } else {
            asm volatile("s_waitcnt vmcnt(0)" ::: "memory");
        }
        __builtin_amdgcn_s_barrier();
        asm volatile("" ::: "memory");
        const char* Ab = smem + buf * 40960;
        const char* Bb = smem + buf * 40960 + 32768;
        #pragma unroll
        for (int kk = 0; kk < 2; ++kk) {
            bf16x8 af[4], bf[2];
            #pragma unroll
            for (int fr = 0; fr < 4; ++fr) {
                int row = wr * 64 + fr * 16 + r;
                af[fr] = *(const bf16x8*)(Ab + row * 128 + (((kk * 4 + h) ^ (row & 7)) << 4));
            }
            #pragma unroll
            for (int fc = 0; fc < 2; ++fc) {
                int rowb = wc * 32 + fc * 16 + r;
                bf[fc] = *(const bf16x8*)(Bb + rowb * 128 + (((kk * 4 + h) ^ (rowb & 7)) << 4));
            }
            #pragma unroll
            for (int fr = 0; fr < 4; ++fr)
                #pragma unroll
                for (int fc = 0; fc < 2; ++fc)
                    acc[fr][fc] = __builtin_amdgcn_mfma_f32_16x16x32_bf16(
                        af[fr], bf[fc], acc[fr][fc], 0, 0, 0);
        }
        asm volatile("" ::: "memory");
        __builtin_amdgcn_s_barrier();
        asm volatile("" ::: "memory");
        buf ^= 1;
    }
    #undef GSTAGE

    const int mw = m0 + wr * 64;
    const int ob0 = bn0 + wc * 32;

    if (EPI == 0) {
        u16* out = (u16*)outp;
        #pragma unroll
        for (int fc = 0; fc < 2; ++fc) {
            int o = ob0 + fc * 16 + r;
            float bs = bias[o];
            #pragma unroll
            for (int fr = 0; fr < 4; ++fr)
                #pragma unroll
                for (int rr = 0; rr < 4; ++rr) {
                    int mrow = mw + fr * 16 + h * 4 + rr;
                    out[(size_t)mrow * NOUT + o] = f2b((acc[fr][fc][rr] + bs) * alpha);
                }
        }
    } else {
        float* tile = (float*)(smem + wave * 8704);   // [32][68] f32
        #pragma unroll
        for (int fc = 0; fc < 2; ++fc)
            #pragma unroll
            for (int fr = 0; fr < 4; ++fr)
                *(f32x4*)(tile + (fc * 16 + r) * 68 + fr * 16 + h * 4) = acc[fr][fc];
        __builtin_amdgcn_s_waitcnt(0);
        float* out = (float*)outp;
        int bb = mw >> 12, nb = mw & 4095;
        #pragma unroll
        for (int g = 0; g < 8; ++g) {
            int chunk = g * 64 + lane;
            int row = chunk >> 4, ns = chunk & 15;
            int o = ob0 + row;
            size_t base = (size_t)bb * CU * NN + (size_t)o * NN + nb + ns * 4;
            f32x4 v = *(const f32x4*)(tile + row * 68 + ns * 4);
            f32x4 u = *(const f32x4*)(unet + base);
            float bs = bias[o];
            f32x4 res;
            #pragma unroll
            for (int rr = 0; rr < 4; ++rr) res[rr] = v[rr] + bs + u[rr];
            *(f32x4*)(out + base) = res;
        }
    }
}

// ---------------- fused K+V projection (KD=1024, 256x64 tile) ----------------
__global__ __launch_bounds__(512, 4) void gemm_kv_kernel(
        const u16* __restrict__ A, const u16* __restrict__ Wk,
        const u16* __restrict__ Wv, const float* __restrict__ bk,
        const float* __restrict__ bv, u16* __restrict__ Kb,
        u16* __restrict__ Vb) {
    const int KD = 1024;
    __shared__ __align__(16) char smem[81920];
    const int t = threadIdx.x;
    const int lane = t & 63, wave = t >> 6;
    const int r = lane & 15, h = lane >> 4;
    const int wr = wave >> 1, wc = wave & 1;
    const int m0 = blockIdx.x * 256;
    const bool isK = blockIdx.y < 4;
    const int bn0 = (isK ? blockIdx.y : (blockIdx.y - 4)) * 64;
    const u16* W = isK ? Wk : Wv;
    const float* bias = isK ? bk : bv;

    int goffA[4], goffB;
    #pragma unroll
    for (int n = 0; n < 4; ++n) {
        int c = n * 512 + t;
        int row = c >> 3, s = c & 7;
        goffA[n] = (m0 + row) * KD + ((s ^ (row & 7)) << 3);
    }
    {
        int row = t >> 3, s = t & 7;
        goffB = (bn0 + row) * KD + ((s ^ (row & 7)) << 3);
    }
    const unsigned wb = (unsigned)(t & ~63) * 16u;

    #define GSTAGE(BUF, KT) do {                                                  \
        _Pragma("unroll")                                                         \
        for (int n_ = 0; n_ < 4; ++n_)                                            \
            async_cp16(A + goffA[n_] + (KT) * 64,                                 \
                       smem + (BUF) * 40960 + n_ * 8192 + wb);                    \
        async_cp16(W + goffB + (KT) * 64,                                         \
                   smem + (BUF) * 40960 + 32768 + wb);                            \
    } while (0)

    f32x4 acc[4][2];
    #pragma unroll
    for (int fr = 0; fr < 4; ++fr)
        #pragma unroll
        for (int fc = 0; fc < 2; ++fc) acc[fr][fc] = (f32x4)0.0f;

    GSTAGE(0, 0);
    int buf = 0;
    for (int kt = 0; kt < 16; ++kt) {
        if (kt < 15) {
            GSTAGE(buf ^ 1, kt + 1);
            asm volatile("s_waitcnt vmcnt(5)" ::: "memory");
        } else {
            asm volatile("s_waitcnt vmcnt(0)" ::: "memory");
        }
        __builtin_amdgcn_s_barrier();
        asm volatile("" ::: "memory");
        const char* Ab = smem + buf * 40960;
        const char* Bb = smem + buf * 40960 + 32768;
        #pragma unroll
        for (int kk = 0; kk < 2; ++kk) {
            bf16x8 af[4], bf[2];
            #pragma unroll
            for (int fr = 0; fr < 4; ++fr) {
                int row = wr * 64 + fr * 16 + r;
                af[fr] = *(const bf16x8*)(Ab + row * 128 + (((kk * 4 + h) ^ (row & 7)) << 4));
            }
            #pragma unroll
            for (int fc = 0; fc < 2; ++fc) {
                int rowb = wc * 32 + fc * 16 + r;
                bf[fc] = *(const bf16x8*)(Bb + rowb * 128 + (((kk * 4 + h) ^ (rowb & 7)) << 4));
            }
            #pragma unroll
            for (int fr = 0; fr < 4; ++fr)
                #pragma unroll
                for (int fc = 0; fc < 2; ++fc)
                    acc[fr][fc] = __builtin_amdgcn_mfma_f32_16x16x32_bf16(
                        af[fr], bf[fc], acc[fr][fc], 0, 0, 0);
        }
        asm volatile("" ::: "memory");
        __builtin_amdgcn_s_barrier();
        asm volatile("" ::: "memory");
        buf ^= 1;
    }
    #undef GSTAGE

    const int mw = m0 + wr * 64;
    const int ob0 = bn0 + wc * 32;

    if (isK) {
        #pragma unroll
        for (int fc = 0; fc < 2; ++fc) {
            int o = ob0 + fc * 16 + r;
            float bs = bias[o];
            #pragma unroll
            for (int fr = 0; fr < 4; ++fr)
                #pragma unroll
                for (int rr = 0; rr < 4; ++rr) {
                    int mrow = mw + fr * 16 + h * 4 + rr;
                    Kb[(size_t)mrow * AD + o] = f2b((acc[fr][fc][rr] + bs));
                }
        }
    } else {
        u16* tile = (u16*)(smem + wave * 4608);
        #pragma unroll
        for (int fc = 0; fc < 2; ++fc) {
            int o = ob0 + fc * 16 + r;
            float bs = bias[o];
            #pragma unroll
            for (int fr = 0; fr < 4; ++fr) {
                u16x4 v4;
                #pragma unroll
                for (int rr = 0; rr < 4; ++rr) v4[rr] = f2b(acc[fr][fc][rr] + bs);
                *(u16x4*)(tile + (fc * 16 + r) * 72 + fr * 16 + h * 4) = v4;
            }
        }
        __builtin_amdgcn_s_waitcnt(0);
        int bb = mw >> 12, nb = mw & 4095;
        #pragma unroll
        for (int g = 0; g < 4; ++g) {
            int chunk = g * 64 + lane;
            int row = chunk >> 3, ns = chunk & 7;
            int ch = ob0 + row;
            int j = nb + ns * 8;
            bf16x8 val = *(const bf16x8*)(tile + row * 72 + ns * 8);
            size_t off = (size_t)bb * CU * NN + (size_t)(ch >> 5) * (NN * 32)
                       + (size_t)(j >> 4) * 512
                       + (size_t)((ch & 31) + ((j >> 3) & 1) * 32) * 8 + (j & 7);
            *(bf16x8*)(Vb + off) = val;
        }
    }
}

// ---------------- flash attention (R19: 3-deep K pipeline) -------------
// 256 blocks x 768 thr (12 waves): waves 0-3 = QK (iw = w>>1, jw = w&1),
// waves 4-11 = PV (iw = pvid>>2, pj = (pvid>>1)&1, cgh = pvid&1, o[5]).
// LDS 117,248 B: kbuf 3x32K @0; pbuf 2 par x 8960 @98304; ml @116224.
// PV body: PV_BODY(i-1) first, then STAGE K[i+2] (newest VM ops -> never
// drained by V-use waits; full-iteration latency cover).
__global__ __launch_bounds__(768, 3) void attn_kernel(
        const u16* __restrict__ Q, const u16* __restrict__ K,
        const u16* __restrict__ V, u16* __restrict__ AO) {
    __shared__ __align__(16) char smem[117248];

    const int t = threadIdx.x;
    const int lane = t & 63;
    const int wave = t >> 6;          // 0..11
    const int r = lane & 31, hi = lane >> 5;

    int linear = blockIdx.x;
    int swz = (linear & 7) * 32 + (linear >> 3);
    int b = swz >> 6;
    int i0 = (swz & 63) * 64;

    const u16* Qb = Q + ((size_t)b * NN + i0) * AD;
    const u16* Kb = K + (size_t)b * NN * AD;
    const u16* Vb = V + (size_t)b * CU * NN;

    // ---- prologue: stage K[0] AND K[1] (4096 chunks) with all 768 threads ----
    {
        #pragma unroll
        for (int n = 0; n < 5; ++n) {
            int id = n * 768 + t;
            if (id < 4096) {
                int tile = id >> 11;
                int idx = id & 2047;
                int row = idx >> 5, c16 = idx & 31;
                async_cp16(Kb + tile * 16384 + row * 256 + ((c16 ^ (row & 31)) << 3),
                           smem + (unsigned)(n * 768 + (t & ~63)) * 16u);
            }
        }
        if (t < 256) {
            int id = 3840 + t;
            int tile = id >> 11;
            int idx = id & 2047;
            int row = idx >> 5, c16 = idx & 31;
            async_cp16(Kb + tile * 16384 + row * 256 + ((c16 ^ (row & 31)) << 3),
                       smem + (unsigned)(3840 + (t & ~63)) * 16u);
        }
    }
    asm volatile("s_waitcnt vmcnt(0)" ::: "memory");
    __builtin_amdgcn_s_barrier();     // K[0], K[1] ready
    asm volatile("" ::: "memory");

    if (wave < 4) {
        // ================= QK role =================
        const int iw = wave >> 1;
        const int jw = wave & 1;
        bf16x8 q[16];
        #pragma unroll
        for (int kk = 0; kk < 16; ++kk)
            q[kk] = *(const bf16x8*)(Qb + (size_t)(iw * 32 + r) * AD + kk * 16 + hi * 8);
        float m = -INFINITY, lsum = 0.0f;

        for (int i = 0; i < 64; ++i) {
            if (i) {
                __builtin_amdgcn_s_barrier();
                asm volatile("" ::: "memory");
            }
            const char* Kt = smem + (i % 3) * 32768 + jw * 16384;
            f32x16 sa = (f32x16)0.0f, sb = (f32x16)0.0f;
            __builtin_amdgcn_s_setprio(1);
            #pragma unroll
            for (int kk = 0; kk < 8; ++kk) {
                bf16x8 k0 = *(const bf16x8*)(Kt + r * 512 + (((2 * kk + hi) ^ r) << 4));
                bf16x8 k1 = *(const bf16x8*)(Kt + r * 512 + (((2 * (kk + 8) + hi) ^ r) << 4));
                sa = __builtin_amdgcn_mfma_f32_32x32x16_bf16(k0, q[kk], sa, 0, 0, 0);
                sb = __builtin_amdgcn_mfma_f32_32x32x16_bf16(k1, q[kk + 8], sb, 0, 0, 0);
            }
            __builtin_amdgcn_s_setprio(0);
            f32x16 s = sa + sb;

            float x0 = fmaxf(s[0], s[1]),   x1 = fmaxf(s[2], s[3]);
            float x2 = fmaxf(s[4], s[5]),   x3 = fmaxf(s[6], s[7]);
            float x4 = fmaxf(s[8], s[9]),   x5 = fmaxf(s[10], s[11]);
            float x6 = fmaxf(s[12], s[13]), x7 = fmaxf(s[14], s[15]);
            float pmax = fmaxf(fmaxf(fmaxf(x0, x1), fmaxf(x2, x3)),
                               fmaxf(fmaxf(x4, x5), fmaxf(x6, x7)));
            pmax = fmaxf(pmax, __shfl_xor(pmax, 32));
            char* pb = smem + 98304 + (i & 1) * 8960;
            int fl = __any(pmax > m + 8.0f) ? 1 : 0;
            if (fl) {
                float mn = fmaxf(m, pmax);
                float al = exp2_fast(m - mn);
                m = mn;
                lsum *= al;
                if (lane < 32) *(float*)(pb + 8192 + (iw * 2 + jw) * 128 + r * 4) = al;
            }
            if (lane == 0) *(int*)(pb + 8704 + (iw * 2 + jw) * 4) = fl;
            float p[16];
            #pragma unroll
            for (int e = 0; e < 16; ++e) p[e] = exp2_fast(s[e] - m);
            float y0 = (p[0] + p[1]) + (p[2] + p[3]);
            float y1 = (p[4] + p[5]) + (p[6] + p[7]);
            float y2 = (p[8] + p[9]) + (p[10] + p[11]);
            float y3 = (p[12] + p[13]) + (p[14] + p[15]);
            float ps = (y0 + y1) + (y2 + y3);
            ps += __shfl_xor(ps, 32);
            lsum += ps;

            #pragma unroll
            for (int ks = 0; ks < 2; ++ks) {
                unsigned a0 = cvt_pk_bf16(p[8 * ks + 0], p[8 * ks + 1]);
                unsigned a1 = cvt_pk_bf16(p[8 * ks + 2], p[8 * ks + 3]);
                unsigned b0 = cvt_pk_bf16(p[8 * ks + 4], p[8 * ks + 5]);
                unsigned b1 = cvt_pk_bf16(p[8 * ks + 6], p[8 * ks + 7]);
                asm("v_permlane32_swap_b32 %0, %1" : "+v"(a0), "+v"(b0));
                asm("v_permlane32_swap_b32 %0, %1" : "+v"(a1), "+v"(b1));
                union { unsigned w[4]; bf16x8 v; } u;
                u.w[0] = a0; u.w[1] = a1; u.w[2] = b0; u.w[3] = b1;
                *(bf16x8*)(pb + (iw * 2 + jw) * 2048 + ks * 1024 + lane * 16) = u.v;
            }
            asm volatile("s_waitcnt lgkmcnt(0)" ::: "memory");
            __builtin_amdgcn_sched_barrier(0);
        }
        __builtin_amdgcn_s_barrier();   // P(63) published
        asm volatile("" ::: "memory");
        if (lane < 32) {
            *(float*)(smem + 116224 + (iw * 2 + jw) * 128 + r * 4) = m;
            *(float*)(smem + 116224 + 512 + (iw * 2 + jw) * 128 + r * 4) = lsum;
        }
        __syncthreads();    // syncA
        __syncthreads();    // syncB
        __syncthreads();    // syncC
    } else {
        // ================= PV role =================
        const int pvid = wave - 4;          // 0..7
        const int iw = pvid >> 2;           // 32-row group
        const int pj = (pvid >> 1) & 1;     // which jw's P
        const int cgh = pvid & 1;           // 160-ch half
        const int tp = t - 256;             // 0..511 over waves 4-11

        int goffp[4];
        #pragma unroll
        for (int n = 0; n < 4; ++n) {
            int id = n * 512 + tp;
            int row = (id >> 5) & 63;
            int c16 = id & 31;
            goffp[n] = row * 256 + ((c16 ^ (row & 31)) << 3);
        }
        const unsigned wbp = (unsigned)(tp & ~63) * 16u;

        #define STAGE(BUF, KP) do {                                               \
            _Pragma("unroll")                                                     \
            for (int n_ = 0; n_ < 4; ++n_)                                        \
                async_cp16((KP) + goffp[n_],                                      \
                           smem + (BUF) * 32768 + n_ * 8192 + wbp);               \
        } while (0)

        f32x16 o[5];
        #pragma unroll
        for (int ct = 0; ct < 5; ++ct) o[ct] = (f32x16)0.0f;
        const u16* vb = Vb + (size_t)(cgh * 5) * 131072 + lane * 8;

        #define PV_BODY(TI) do {                                                  \
            const char* pb = smem + 98304 + ((TI) & 1) * 8960;                    \
            int fl = *(volatile const int*)(pb + 8704 + (iw * 2 + pj) * 4);       \
            bf16x8 pf0 = *(const bf16x8*)(pb + (iw * 2 + pj) * 2048 + lane * 16); \
            bf16x8 pf1 = *(const bf16x8*)(pb + (iw * 2 + pj) * 2048 + 1024 +      \
                                          lane * 16);                             \
            bf16x8 vfA[5], vfB[5];                                                \
            _Pragma("unroll")                                                     \
            for (int c = 0; c < 5; ++c)                                           \
                vfA[c] = *(const bf16x8*)(vb + (size_t)c * 131072 +               \
                                          ((TI) * 4 + pj * 2 + 0) * 512);         \
            _Pragma("unroll")                                                     \
            for (int c = 0; c < 5; ++c)                                           \
                vfB[c] = *(const bf16x8*)(vb + (size_t)c * 131072 +               \
                                          ((TI) * 4 + pj * 2 + 1) * 512);         \
            if (fl) {                                                             \
                float alv = *(volatile const float*)(pb + 8192 +                  \
                                (iw * 2 + pj) * 128 + (lane & 31) * 4);           \
                _Pragma("unroll")                                                 \
                for (int ct = 0; ct < 5; ++ct) o[ct] *= alv;                      \
            }                                                                     \
            __builtin_amdgcn_s_setprio(1);                                        \
            _Pragma("unroll")                                                     \
            for (int ct = 0; ct < 5; ++ct)                                        \
                o[ct] = __builtin_amdgcn_mfma_f32_32x32x16_bf16(vfA[ct], pf0,     \
                                                                o[ct], 0, 0, 0); \
            _Pragma("unroll")                                                     \
            for (int ct = 0; ct < 5; ++ct)                                        \
                o[ct] = __builtin_amdgcn_mfma_f32_32x32x16_bf16(vfB[ct], pf1,     \
                                                                o[ct], 0, 0, 0); \
            __builtin_amdgcn_s_setprio(0);                                        \
        } while (0)

        for (int i = 0; i < 64; ++i) {
            if (i) {
                __builtin_amdgcn_s_barrier();
                asm volatile("" ::: "memory");
            }
            if (i >= 1) PV_BODY(i - 1);
            if (i <= 61) {
                STAGE((i + 2) % 3, Kb + (i + 2) * 16384);
                asm volatile("s_waitcnt vmcnt(4)" ::: "memory");
            } else {
                asm volatile("s_waitcnt vmcnt(0)" ::: "memory");
            }
        }
        __builtin_amdgcn_s_barrier();   // P(63) published
        asm volatile("" ::: "memory");
        PV_BODY(63);

        __syncthreads();    // syncA: m/l published, kbuf dead
        float m0 = *(const float*)(smem + 116224 + (iw * 2 + pj) * 128 + r * 4);
        float l0 = *(const float*)(smem + 116224 + 512 + (iw * 2 + pj) * 128 + r * 4);
        float m1 = *(const float*)(smem + 116224 + (iw * 2 + (pj ^ 1)) * 128 + r * 4);
        float l1 = *(const float*)(smem + 116224 + 512 + (iw * 2 + (pj ^ 1)) * 128 + r * 4);
        float M = fmaxf(m0, m1);
        float fsc = exp2_fast(m0 - M);
        float fo = exp2_fast(m1 - M);
        float inv = 1.0f / (l0 * fsc + l1 * fo);

        u16* fb = (u16*)smem;              // [64][328] bf16, in-place merge
        if (pj == 1) {
            #pragma unroll
            for (int ct = 0; ct < 5; ++ct)
                #pragma unroll
                for (int e = 0; e < 16; ++e) {
                    int c = cgh * 160 + ct * 32 + (e & 3) + 8 * (e >> 2) + 4 * hi;
                    fb[(iw * 32 + r) * 328 + c] = f2b(o[ct][e] * fsc);
                }
        }
        __syncthreads();    // syncB
        if (pj == 0) {
            #pragma unroll
            for (int ct = 0; ct < 5; ++ct)
                #pragma unroll
                for (int g = 0; g < 4; ++g) {
                    int cb = cgh * 160 + ct * 32 + 8 * g + 4 * hi;
                    u16* fr = &fb[(iw * 32 + r) * 328 + cb];
                    float v0 = (o[ct][4 * g + 0] * fsc + b2f(fr[0])) * inv;
                    float v1 = (o[ct][4 * g + 1] * fsc + b2f(fr[1])) * inv;
                    float v2 = (o[ct][4 * g + 2] * fsc + b2f(fr[2])) * inv;
                    float v3 = (o[ct][4 * g + 3] * fsc + b2f(fr[3])) * inv;
                    *(unsigned*)(fr) = cvt_pk_bf16(v0, v1);
                    *(unsigned*)(fr + 2) = cvt_pk_bf16(v2, v3);
                }
        }
        __syncthreads();    // syncC
        #undef PV_BODY
        #undef STAGE
    }

    // ---- common: store AO (64 q-rows x 320 ch) from smem [64][328] ----
    const u16* ob = (const u16*)smem;
    u16* AOb = AO + ((size_t)b * NN + i0) * CU;
    #pragma unroll
    for (int n = 0; n < 3; ++n) {
        int id = n * 768 + t;
        int row = id / 40, c8 = id % 40;
        bf16x8 val = *(const bf16x8*)(ob + row * 328 + c8 * 8);
        *(bf16x8*)(AOb + (size_t)row * CU + c8 * 8) = val;
    }
    if (t < 256) {
        int id = 2304 + t;
        int row = id / 40, c8 = id % 40;
        bf16x8 val = *(const bf16x8*)(ob + row * 328 + c8 * 8);
        *(bf16x8*)(AOb + (size_t)row * CU + c8 * 8) = val;
    }
}

extern "C" void kernel_launch(void* const* d_in, const int* in_sizes, int n_in,
                              void* d_out, int out_size, void* d_ws, size_t ws_size,
                              hipStream_t stream) {
    const float* unet  = (const float*)d_in[0];
    const float* janus = (const float*)d_in[1];
    const float* Wq = (const float*)d_in[2];
    const float* bq = (const float*)d_in[3];
    const float* Wk = (const float*)d_in[4];
    const float* bk = (const float*)d_in[5];
    const float* Wv = (const float*)d_in[6];
    const float* bv = (const float*)d_in[7];
    const float* Wo = (const float*)d_in[8];
    const float* bo = (const float*)d_in[9];
    float* out = (float*)d_out;

    char* ws = (char*)d_ws;
    u16* Xu  = (u16*)(ws + XU_OFF);
    u16* Xj  = (u16*)(ws + XJ_OFF);
    u16* Qb  = (u16*)(ws + QB_OFF);
    u16* Kb  = (u16*)(ws + KB_OFF);
    u16* Vb  = (u16*)(ws + VB_OFF);
    u16* wq  = (u16*)(ws + WQ_OFF);
    u16* wk  = (u16*)(ws + WK_OFF);
    u16* wv  = (u16*)(ws + WV_OFF);
    u16* wo  = (u16*)(ws + WO_OFF);
    u16* AO  = (u16*)(ws + AO_OFF);

    // fused prep: transposes + weight cast
    prep_kernel<<<8400, 256, 0, stream>>>(unet, janus, Wq, Wk, Wv, Wo,
                                          Xu, Xj, wq, wk, wv, wo);

    // Q pre-scaled by (1/16) * log2(e) so softmax runs in exp2 domain
    gemm_kernel<0, 320, 256><<<dim3(64, 4), 512, 0, stream>>>(
        Xu, wq, bq, Qb, nullptr, 0.0901684411f);

    // fused K + V projections
    gemm_kv_kernel<<<dim3(64, 9), 512, 0, stream>>>(
        Xj, wk, wv, bk, bv, Kb, Vb);

    attn_kernel<<<256, 768, 0, stream>>>(Qb, Kb, Vb, AO);

    gemm_kernel<2, 320, 320><<<dim3(64, 5), 512, 0, stream>>>(
        AO, wo, bo, out, unet, 1.0f);
}

// Round 22
// 167.594 us; speedup vs baseline: 1.0991x; 1.0275x over previous
//
#include <hip/hip_runtime.h>
#include <hip/hip_bf16.h>
#include <math.h>

// ---------------------------------------------------------------------------
// CrossModalAttention on MI355X (gfx950)
//   B=4, Cu=320, Cj=1024, H=W=64 (N=4096), ATTN_DIM=256, scale = 1/16
// Round 22: R19/R21 attn (best, 100us) unchanged. Q projection merged into
// the K+V projection kernel (grid 64x13, runtime KD 320/1024) so the three
// independent projections run concurrently and fill the machine.
// ---------------------------------------------------------------------------

typedef unsigned short u16;
typedef __attribute__((ext_vector_type(8))) short bf16x8;
typedef __attribute__((ext_vector_type(4))) float f32x4;
typedef __attribute__((ext_vector_type(16))) float f32x16;
typedef __attribute__((ext_vector_type(4))) unsigned short u16x4;

#define NB 4
#define CU 320
#define CJ 1024
#define NN 4096
#define AD 256

// ws layout (bytes)
#define XU_OFF 0u
#define XJ_OFF 10485760u
#define QB_OFF 44040192u
#define KB_OFF 52428800u
#define VB_OFF 60817408u
#define WQ_OFF 71303168u
#define WK_OFF 71467008u
#define WV_OFF 71991296u
#define WO_OFF 72646656u
#define AO_OFF XU_OFF

__device__ __forceinline__ u16 f2b(float f) {
    union { float f; unsigned u; } v; v.f = f;
    unsigned u = v.u;
    unsigned r = (u + 0x7fffu + ((u >> 16) & 1u)) >> 16;
    return (u16)r;
}

__device__ __forceinline__ float b2f(u16 x) {
    union { unsigned u; float f; } v; v.u = ((unsigned)x) << 16;
    return v.f;
}

__device__ __forceinline__ unsigned cvt_pk_bf16(float lo, float hi) {
    unsigned r;
    asm("v_cvt_pk_bf16_f32 %0, %1, %2" : "=v"(r) : "v"(lo), "v"(hi));
    return r;
}

__device__ __forceinline__ float exp2_fast(float x) {
    float r;
    asm("v_exp_f32 %0, %1" : "=v"(r) : "v"(x));
    return r;
}

__device__ __forceinline__ void async_cp16(const u16* g, char* l) {
    __builtin_amdgcn_global_load_lds(
        (const __attribute__((address_space(1))) unsigned int*)g,
        (__attribute__((address_space(3))) unsigned int*)l, 16, 0, 0);
}

// ---------------- fused prep: transpose unet, transpose janus, weight cast ----
__global__ __launch_bounds__(256) void prep_kernel(
        const float* __restrict__ unet, const float* __restrict__ janus,
        const float* __restrict__ Wq, const float* __restrict__ Wk,
        const float* __restrict__ Wv, const float* __restrict__ Wo,
        u16* __restrict__ Xu, u16* __restrict__ Xj,
        u16* __restrict__ wq, u16* __restrict__ wk,
        u16* __restrict__ wv, u16* __restrict__ wo) {
    __shared__ float tile[64][65];
    int bid = blockIdx.x;
    int t = threadIdx.x;

    if (bid < 5376) {
        const float* src;
        u16* dst;
        int C, x, y, z;
        if (bid < 1280) {
            z = bid / 320; int rem = bid % 320; y = rem / 64; x = rem % 64;
            C = CU; src = unet + (size_t)z * CU * NN; dst = Xu + (size_t)z * NN * CU;
        } else {
            int idx = bid - 1280;
            z = idx / 1024; int rem = idx % 1024; y = rem / 64; x = rem % 64;
            C = CJ; src = janus + (size_t)z * CJ * NN; dst = Xj + (size_t)z * NN * CJ;
        }
        int n0 = x * 64, c0 = y * 64;
        int nl = t & 63, cl = t >> 6;
        #pragma unroll
        for (int k = 0; k < 16; ++k) {
            int c = cl + k * 4;
            tile[c][nl] = src[(size_t)(c0 + c) * NN + n0 + nl];
        }
        __syncthreads();
        int cl2 = t & 63, nl2 = t >> 6;
        #pragma unroll
        for (int k = 0; k < 16; ++k) {
            int n = nl2 + k * 4;
            dst[(size_t)(n0 + n) * C + c0 + cl2] = f2b(tile[cl2][n]);
        }
        return;
    }
    int id = (bid - 5376) * 256 + t;
    if (id < 81920) { wq[id] = f2b(Wq[id]); return; }
    id -= 81920;
    if (id < 262144) { wk[id] = f2b(Wk[id]); return; }
    id -= 262144;
    if (id < 327680) { wv[id] = f2b(Wv[id]); return; }
    id -= 327680;
    if (id < 102400) { wo[id] = f2b(Wo[id]); }
}

// ---------------- final GEMM: out = AO(16384x320) @ Wo^T + unet ----------------
// 256x64 tile, BK=64, 8 waves (wr4 x wc2, 64x32 each), 2 blocks/CU.
template <int KD, int NOUT>
__global__ __launch_bounds__(512, 4) void gemm_final_kernel(
        const u16* __restrict__ A, const u16* __restrict__ W,
        const float* __restrict__ bias, float* __restrict__ outp,
        const float* __restrict__ unet) {
    __shared__ __align__(16) char smem[81920];
    const int t = threadIdx.x;
    const int lane = t & 63, wave = t >> 6;
    const int r = lane & 15, h = lane >> 4;
    const int wr = wave >> 1, wc = wave & 1;
    const int m0 = blockIdx.x * 256;
    const int bn0 = blockIdx.y * 64;

    int goffA[4], goffB;
    #pragma unroll
    for (int n = 0; n < 4; ++n) {
        int c = n * 512 + t;
        int row = c >> 3, s = c & 7;
        goffA[n] = (m0 + row) * KD + ((s ^ (row & 7)) << 3);
    }
    {
        int row = t >> 3, s = t & 7;
        goffB = (bn0 + row) * KD + ((s ^ (row & 7)) << 3);
    }
    const unsigned wb = (unsigned)(t & ~63) * 16u;

    #define GSTAGE(BUF, KT) do {                                                  \
        _Pragma("unroll")                                                         \
        for (int n_ = 0; n_ < 4; ++n_)                                            \
            async_cp16(A + goffA[n_] + (KT) * 64,                                 \
                       smem + (BUF) * 40960 + n_ * 8192 + wb);                    \
        async_cp16(W + goffB + (KT) * 64,                                         \
                   smem + (BUF) * 40960 + 32768 + wb);                            \
    } while (0)

    f32x4 acc[4][2];
    #pragma unroll
    for (int fr = 0; fr < 4; ++fr)
        #pragma unroll
        for (int fc = 0; fc < 2; ++fc) acc[fr][fc] = (f32x4)0.0f;

    GSTAGE(0, 0);
    int buf = 0;
    const int KS = KD / 64;
    for (int kt = 0; kt < KS; ++kt) {
        if (kt < KS - 1) {
            GSTAGE(buf ^ 1, kt + 1);
            asm volatile("s_waitcnt vmcnt(5)" ::: "memory");
        } else {
            asm volatile("s_waitcnt vmcnt(0)" ::: "memory");
        }
        __builtin_amdgcn_s_barrier();
        asm volatile("" ::: "memory");
        const char* Ab = smem + buf * 40960;
        const char* Bb = smem + buf * 40960 + 32768;
        #pragma unroll
        for (int kk = 0; kk < 2; ++kk) {
            bf16x8 af[4], bf[2];
            #pragma unroll
            for (int fr = 0; fr < 4; ++fr) {
                int row = wr * 64 + fr * 16 + r;
                af[fr] = *(const bf16x8*)(Ab + row * 128 + (((kk * 4 + h) ^ (row & 7)) << 4));
            }
            #pragma unroll
            for (int fc = 0; fc < 2; ++fc) {
                int rowb = wc * 32 + fc * 16 + r;
                bf[fc] = *(const bf16x8*)(Bb + rowb * 128 + (((kk * 4 + h) ^ (rowb & 7)) << 4));
            }
            #pragma unroll
            for (int fr = 0; fr < 4; ++fr)
                #pragma unroll
                for (int fc = 0; fc < 2; ++fc)
                    acc[fr][fc] = __builtin_amdgcn_mfma_f32_16x16x32_bf16(
                        af[fr], bf[fc], acc[fr][fc], 0, 0, 0);
        }
        asm volatile("" ::: "memory");
        __builtin_amdgcn_s_barrier();
        asm volatile("" ::: "memory");
        buf ^= 1;
    }
    #undef GSTAGE

    const int mw = m0 + wr * 64;
    const int ob0 = bn0 + wc * 32;

    float* tile = (float*)(smem + wave * 8704);   // [32][68] f32
    #pragma unroll
    for (int fc = 0; fc < 2; ++fc)
        #pragma unroll
        for (int fr = 0; fr < 4; ++fr)
            *(f32x4*)(tile + (fc * 16 + r) * 68 + fr * 16 + h * 4) = acc[fr][fc];
    __builtin_amdgcn_s_waitcnt(0);
    int bb = mw >> 12, nb = mw & 4095;
    #pragma unroll
    for (int g = 0; g < 8; ++g) {
        int chunk = g * 64 + lane;
        int row = chunk >> 4, ns = chunk & 15;
        int o = ob0 + row;
        size_t base = (size_t)bb * CU * NN + (size_t)o * NN + nb + ns * 4;
        f32x4 v = *(const f32x4*)(tile + row * 68 + ns * 4);
        f32x4 u = *(const f32x4*)(unet + base);
        float bs = bias[o];
        f32x4 res;
        #pragma unroll
        for (int rr = 0; rr < 4; ++rr) res[rr] = v[rr] + bs + u[rr];
        *(f32x4*)(outp + base) = res;
    }
}

// ---------------- fused Q+K+V projection (256x64 tile, runtime KD) ----------
// grid (64, 13): y<4 -> K (Xj,KD=1024, bf16 [M][256]);
//                y in [4,9) -> V (Xj,KD=1024, fragment order V');
//                y in [9,13) -> Q (Xu,KD=320, bf16 [M][256], alpha=log2e/16).
__global__ __launch_bounds__(512, 4) void gemm_qkv_kernel(
        const u16* __restrict__ Xu, const u16* __restrict__ Xj,
        const u16* __restrict__ wq, const u16* __restrict__ wk,
        const u16* __restrict__ wv, const float* __restrict__ bq,
        const float* __restrict__ bk, const float* __restrict__ bv,
        u16* __restrict__ Qb, u16* __restrict__ Kb, u16* __restrict__ Vb) {
    __shared__ __align__(16) char smem[81920];
    const int t = threadIdx.x;
    const int lane = t & 63, wave = t >> 6;
    const int r = lane & 15, h = lane >> 4;
    const int wr = wave >> 1, wc = wave & 1;
    const int m0 = blockIdx.x * 256;

    const int ytile = blockIdx.y;
    int mode, bn0, KD;
    const u16 *A, *W;
    const float* bias;
    float alpha;
    if (ytile < 4) {
        mode = 0; bn0 = ytile * 64; KD = 1024;
        A = Xj; W = wk; bias = bk; alpha = 1.0f;
    } else if (ytile < 9) {
        mode = 1; bn0 = (ytile - 4) * 64; KD = 1024;
        A = Xj; W = wv; bias = bv; alpha = 1.0f;
    } else {
        mode = 2; bn0 = (ytile - 9) * 64; KD = 320;
        A = Xu; W = wq; bias = bq; alpha = 0.0901684411f;  // (1/16)*log2(e)
    }

    int goffA[4], goffB;
    #pragma unroll
    for (int n = 0; n < 4; ++n) {
        int c = n * 512 + t;
        int row = c >> 3, s = c & 7;
        goffA[n] = (m0 + row) * KD + ((s ^ (row & 7)) << 3);
    }
    {
        int row = t >> 3, s = t & 7;
        goffB = (bn0 + row) * KD + ((s ^ (row & 7)) << 3);
    }
    const unsigned wb = (unsigned)(t & ~63) * 16u;

    #define GSTAGE(BUF, KT) do {                                                  \
        _Pragma("unroll")                                                         \
        for (int n_ = 0; n_ < 4; ++n_)                                            \
            async_cp16(A + goffA[n_] + (KT) * 64,                                 \
                       smem + (BUF) * 40960 + n_ * 8192 + wb);                    \
        async_cp16(W + goffB + (KT) * 64,                                         \
                   smem + (BUF) * 40960 + 32768 + wb);                            \
    } while (0)

    f32x4 acc[4][2];
    #pragma unroll
    for (int fr = 0; fr < 4; ++fr)
        #pragma unroll
        for (int fc = 0; fc < 2; ++fc) acc[fr][fc] = (f32x4)0.0f;

    GSTAGE(0, 0);
    int buf = 0;
    const int KS = KD / 64;       // 16 (K/V) or 5 (Q), runtime
    for (int kt = 0; kt < KS; ++kt) {
        if (kt < KS - 1) {
            GSTAGE(buf ^ 1, kt + 1);
            asm volatile("s_waitcnt vmcnt(5)" ::: "memory");
        } else {
            asm volatile("s_waitcnt vmcnt(0)" ::: "memory");
        }
        __builtin_amdgcn_s_barrier();
        asm volatile("" ::: "memory");
        const char* Ab = smem + buf * 40960;
        const char* Bb = smem + buf * 40960 + 32768;
        #pragma unroll
        for (int kk = 0; kk < 2; ++kk) {
            bf16x8 af[4], bf[2];
            #pragma unroll
            for (int fr = 0; fr < 4; ++fr) {
                int row = wr * 64 + fr * 16 + r;
                af[fr] = *(const bf16x8*)(Ab + row * 128 + (((kk * 4 + h) ^ (row & 7)) << 4));
            }
            #pragma unroll
            for (int fc = 0; fc < 2; ++fc) {
                int rowb = wc * 32 + fc * 16 + r;
                bf[fc] = *(const bf16x8*)(Bb + rowb * 128 + (((kk * 4 + h) ^ (rowb & 7)) << 4));
            }
            #pragma unroll
            for (int fr = 0; fr < 4; ++fr)
                #pragma unroll
                for (int fc = 0; fc < 2; ++fc)
                    acc[fr][fc] = __builtin_amdgcn_mfma_f32_16x16x32_bf16(
                        af[fr], bf[fc], acc[fr][fc], 0, 0, 0);
        }
        asm volatile("" ::: "memory");
        __builtin_amdgcn_s_barrier();
        asm volatile("" ::: "memory");
        buf ^= 1;
    }
    #undef GSTAGE

    const int mw = m0 + wr * 64;
    const int ob0 = bn0 + wc * 32;

    if (mode != 1) {
        // Q or K: bf16 [M][256], val = (acc + bias) * alpha
        u16* out = (mode == 2) ? Qb : Kb;
        #pragma unroll
        for (int fc = 0; fc < 2; ++fc) {
            int o = ob0 + fc * 16 + r;
            float bs = bias[o];
            #pragma unroll
            for (int fr = 0; fr < 4; ++fr)
                #pragma unroll
                for (int rr = 0; rr < 4; ++rr) {
                    int mrow = mw + fr * 16 + h * 4 + rr;
                    out[(size_t)mrow * AD + o] = f2b((acc[fr][fc][rr] + bs) * alpha);
                }
        }
    } else {
        // V: transpose via wave-local LDS tile then fragment-order store
        u16* tile = (u16*)(smem + wave * 4608);
        #pragma unroll
        for (int fc = 0; fc < 2; ++fc) {
            int o = ob0 + fc * 16 + r;
            float bs = bias[o];
            #pragma unroll
            for (int fr = 0; fr < 4; ++fr) {
                u16x4 v4;
                #pragma unroll
                for (int rr = 0; rr < 4; ++rr) v4[rr] = f2b(acc[fr][fc][rr] + bs);
                *(u16x4*)(tile + (fc * 16 + r) * 72 + fr * 16 + h * 4) = v4;
            }
        }
        __builtin_amdgcn_s_waitcnt(0);
        int bb = mw >> 12, nb = mw & 4095;
        #pragma unroll
        for (int g = 0; g < 4; ++g) {
            int chunk = g * 64 + lane;
            int row = chunk >> 3, ns = chunk & 7;
            int ch = ob0 + row;
            int j = nb + ns * 8;
            bf16x8 val = *(const bf16x8*)(tile + row * 72 + ns * 8);
            size_t off = (size_t)bb * CU * NN + (size_t)(ch >> 5) * (NN * 32)
                       + (size_t)(j >> 4) * 512
                       + (size_t)((ch & 31) + ((j >> 3) & 1) * 32) * 8 + (j & 7);
            *(bf16x8*)(Vb + off) = val;
        }
    }
}

// ---------------- flash attention (R19: 3-deep K pipeline) -------------
// 256 blocks x 768 thr (12 waves): waves 0-3 = QK (iw = w>>1, jw = w&1),
// waves 4-11 = PV (iw = pvid>>2, pj = (pvid>>1)&1, cgh = pvid&1, o[5]).
// LDS 117,248 B: kbuf 3x32K @0; pbuf 2 par x 8960 @98304; ml @116224.
// PV body: PV_BODY(i-1) first, then STAGE K[i+2] (newest VM ops -> never
// drained by V-use waits; full-iteration latency cover).
__global__ __launch_bounds__(768, 3) void attn_kernel(
        const u16* __restrict__ Q, const u16* __restrict__ K,
        const u16* __restrict__ V, u16* __restrict__ AO) {
    __shared__ __align__(16) char smem[117248];

    const int t = threadIdx.x;
    const int lane = t & 63;
    const int wave = t >> 6;          // 0..11
    const int r = lane & 31, hi = lane >> 5;

    int linear = blockIdx.x;
    int swz = (linear & 7) * 32 + (linear >> 3);
    int b = swz >> 6;
    int i0 = (swz & 63) * 64;

    const u16* Qb = Q + ((size_t)b * NN + i0) * AD;
    const u16* Kb = K + (size_t)b * NN * AD;
    const u16* Vb = V + (size_t)b * CU * NN;

    // ---- prologue: stage K[0] AND K[1] (4096 chunks) with all 768 threads ----
    {
        #pragma unroll
        for (int n = 0; n < 5; ++n) {
            int id = n * 768 + t;
            if (id < 4096) {
                int tile = id >> 11;
                int idx = id & 2047;
                int row = idx >> 5, c16 = idx & 31;
                async_cp16(Kb + tile * 16384 + row * 256 + ((c16 ^ (row & 31)) << 3),
                           smem + (unsigned)(n * 768 + (t & ~63)) * 16u);
            }
        }
        if (t < 256) {
            int id = 3840 + t;
            int tile = id >> 11;
            int idx = id & 2047;
            int row = idx >> 5, c16 = idx & 31;
            async_cp16(Kb + tile * 16384 + row * 256 + ((c16 ^ (row & 31)) << 3),
                       smem + (unsigned)(3840 + (t & ~63)) * 16u);
        }
    }
    asm volatile("s_waitcnt vmcnt(0)" ::: "memory");
    __builtin_amdgcn_s_barrier();     // K[0], K[1] ready
    asm volatile("" ::: "memory");

    if (wave < 4) {
        // ================= QK role =================
        const int iw = wave >> 1;
        const int jw = wave & 1;
        bf16x8 q[16];
        #pragma unroll
        for (int kk = 0; kk < 16; ++kk)
            q[kk] = *(const bf16x8*)(Qb + (size_t)(iw * 32 + r) * AD + kk * 16 + hi * 8);
        float m = -INFINITY, lsum = 0.0f;

        for (int i = 0; i < 64; ++i) {
            if (i) {
                __builtin_amdgcn_s_barrier();
                asm volatile("" ::: "memory");
            }
            const char* Kt = smem + (i % 3) * 32768 + jw * 16384;
            f32x16 sa = (f32x16)0.0f, sb = (f32x16)0.0f;
            __builtin_amdgcn_s_setprio(1);
            #pragma unroll
            for (int kk = 0; kk < 8; ++kk) {
                bf16x8 k0 = *(const bf16x8*)(Kt + r * 512 + (((2 * kk + hi) ^ r) << 4));
                bf16x8 k1 = *(const bf16x8*)(Kt + r * 512 + (((2 * (kk + 8) + hi) ^ r) << 4));
                sa = __builtin_amdgcn_mfma_f32_32x32x16_bf16(k0, q[kk], sa, 0, 0, 0);
                sb = __builtin_amdgcn_mfma_f32_32x32x16_bf16(k1, q[kk + 8], sb, 0, 0, 0);
            }
            __builtin_amdgcn_s_setprio(0);
            f32x16 s = sa + sb;

            float x0 = fmaxf(s[0], s[1]),   x1 = fmaxf(s[2], s[3]);
            float x2 = fmaxf(s[4], s[5]),   x3 = fmaxf(s[6], s[7]);
            float x4 = fmaxf(s[8], s[9]),   x5 = fmaxf(s[10], s[11]);
            float x6 = fmaxf(s[12], s[13]), x7 = fmaxf(s[14], s[15]);
            float pmax = fmaxf(fmaxf(fmaxf(x0, x1), fmaxf(x2, x3)),
                               fmaxf(fmaxf(x4, x5), fmaxf(x6, x7)));
            pmax = fmaxf(pmax, __shfl_xor(pmax, 32));
            char* pb = smem + 98304 + (i & 1) * 8960;
            int fl = __any(pmax > m + 8.0f) ? 1 : 0;
            if (fl) {
                float mn = fmaxf(m, pmax);
                float al = exp2_fast(m - mn);
                m = mn;
                lsum *= al;
                if (lane < 32) *(float*)(pb + 8192 + (iw * 2 + jw) * 128 + r * 4) = al;
            }
            if (lane == 0) *(int*)(pb + 8704 + (iw * 2 + jw) * 4) = fl;
            float p[16];
            #pragma unroll
            for (int e = 0; e < 16; ++e) p[e] = exp2_fast(s[e] - m);
            float y0 = (p[0] + p[1]) + (p[2] + p[3]);
            float y1 = (p[4] + p[5]) + (p[6] + p[7]);
            float y2 = (p[8] + p[9]) + (p[10] + p[11]);
            float y3 = (p[12] + p[13]) + (p[14] + p[15]);
            float ps = (y0 + y1) + (y2 + y3);
            ps += __shfl_xor(ps, 32);
            lsum += ps;

            #pragma unroll
            for (int ks = 0; ks < 2; ++ks) {
                unsigned a0 = cvt_pk_bf16(p[8 * ks + 0], p[8 * ks + 1]);
                unsigned a1 = cvt_pk_bf16(p[8 * ks + 2], p[8 * ks + 3]);
                unsigned b0 = cvt_pk_bf16(p[8 * ks + 4], p[8 * ks + 5]);
                unsigned b1 = cvt_pk_bf16(p[8 * ks + 6], p[8 * ks + 7]);
                asm("v_permlane32_swap_b32 %0, %1" : "+v"(a0), "+v"(b0));
                asm("v_permlane32_swap_b32 %0, %1" : "+v"(a1), "+v"(b1));
                union { unsigned w[4]; bf16x8 v; } u;
                u.w[0] = a0; u.w[1] = a1; u.w[2] = b0; u.w[3] = b1;
                *(bf16x8*)(pb + (iw * 2 + jw) * 2048 + ks * 1024 + lane * 16) = u.v;
            }
            asm volatile("s_waitcnt lgkmcnt(0)" ::: "memory");
            __builtin_amdgcn_sched_barrier(0);
        }
        __builtin_amdgcn_s_barrier();   // P(63) published
        asm volatile("" ::: "memory");
        if (lane < 32) {
            *(float*)(smem + 116224 + (iw * 2 + jw) * 128 + r * 4) = m;
            *(float*)(smem + 116224 + 512 + (iw * 2 + jw) * 128 + r * 4) = lsum;
        }
        __syncthreads();    // syncA
        __syncthreads();    // syncB
        __syncthreads();    // syncC
    } else {
        // ================= PV role =================
        const int pvid = wave - 4;          // 0..7
        const int iw = pvid >> 2;           // 32-row group
        const int pj = (pvid >> 1) & 1;     // which jw's P
        const int cgh = pvid & 1;           // 160-ch half
        const int tp = t - 256;             // 0..511 over waves 4-11

        int goffp[4];
        #pragma unroll
        for (int n = 0; n < 4; ++n) {
            int id = n * 512 + tp;
            int row = (id >> 5) & 63;
            int c16 = id & 31;
            goffp[n] = row * 256 + ((c16 ^ (row & 31)) << 3);
        }
        const unsigned wbp = (unsigned)(tp & ~63) * 16u;

        #define STAGE(BUF, KP) do {                                               \
            _Pragma("unroll")                                                     \
            for (int n_ = 0; n_ < 4; ++n_)                                        \
                async_cp16((KP) + goffp[n_],                                      \
                           smem + (BUF) * 32768 + n_ * 8192 + wbp);               \
        } while (0)

        f32x16 o[5];
        #pragma unroll
        for (int ct = 0; ct < 5; ++ct) o[ct] = (f32x16)0.0f;
        const u16* vb = Vb + (size_t)(cgh * 5) * 131072 + lane * 8;

        #define PV_BODY(TI) do {                                                  \
            const char* pb = smem + 98304 + ((TI) & 1) * 8960;                    \
            int fl = *(volatile const int*)(pb + 8704 + (iw * 2 + pj) * 4);       \
            bf16x8 pf0 = *(const bf16x8*)(pb + (iw * 2 + pj) * 2048 + lane * 16); \
            bf16x8 pf1 = *(const bf16x8*)(pb + (iw * 2 + pj) * 2048 + 1024 +      \
                                          lane * 16);                             \
            bf16x8 vfA[5], vfB[5];                                                \
            _Pragma("unroll")                                                     \
            for (int c = 0; c < 5; ++c)                                           \
                vfA[c] = *(const bf16x8*)(vb + (size_t)c * 131072 +               \
                                          ((TI) * 4 + pj * 2 + 0) * 512);         \
            _Pragma("unroll")                                                     \
            for (int c = 0; c < 5; ++c)                                           \
                vfB[c] = *(const bf16x8*)(vb + (size_t)c * 131072 +               \
                                          ((TI) * 4 + pj * 2 + 1) * 512);         \
            if (fl) {                                                             \
                float alv = *(volatile const float*)(pb + 8192 +                  \
                                (iw * 2 + pj) * 128 + (lane & 31) * 4);           \
                _Pragma("unroll")                                                 \
                for (int ct = 0; ct < 5; ++ct) o[ct] *= alv;                      \
            }                                                                     \
            __builtin_amdgcn_s_setprio(1);                                        \
            _Pragma("unroll")                                                     \
            for (int ct = 0; ct < 5; ++ct)                                        \
                o[ct] = __builtin_amdgcn_mfma_f32_32x32x16_bf16(vfA[ct], pf0,     \
                                                                o[ct], 0, 0, 0); \
            _Pragma("unroll")                                                     \
            for (int ct = 0; ct < 5; ++ct)                                        \
                o[ct] = __builtin_amdgcn_mfma_f32_32x32x16_bf16(vfB[ct], pf1,     \
                                                                o[ct], 0, 0, 0); \
            __builtin_amdgcn_s_setprio(0);                                        \
        } while (0)

        for (int i = 0; i < 64; ++i) {
            if (i) {
                __builtin_amdgcn_s_barrier();
                asm volatile("" ::: "memory");
            }
            if (i >= 1) PV_BODY(i - 1);
            if (i <= 61) {
                STAGE((i + 2) % 3, Kb + (i + 2) * 16384);
                asm volatile("s_waitcnt vmcnt(4)" ::: "memory");
            } else {
                asm volatile("s_waitcnt vmcnt(0)" ::: "memory");
            }
        }
        __builtin_amdgcn_s_barrier();   // P(63) published
        asm volatile("" ::: "memory");
        PV_BODY(63);

        __syncthreads();    // syncA: m/l published, kbuf dead
        float m0 = *(const float*)(smem + 116224 + (iw * 2 + pj) * 128 + r * 4);
        float l0 = *(const float*)(smem + 116224 + 512 + (iw * 2 + pj) * 128 + r * 4);
        float m1 = *(const float*)(smem + 116224 + (iw * 2 + (pj ^ 1)) * 128 + r * 4);
        float l1 = *(const float*)(smem + 116224 + 512 + (iw * 2 + (pj ^ 1)) * 128 + r * 4);
        float M = fmaxf(m0, m1);
        float fsc = exp2_fast(m0 - M);
        float fo = exp2_fast(m1 - M);
        float inv = 1.0f / (l0 * fsc + l1 * fo);

        u16* fb = (u16*)smem;              // [64][328] bf16, in-place merge
        if (pj == 1) {
            #pragma unroll
            for (int ct = 0; ct < 5; ++ct)
                #pragma unroll
                for (int e = 0; e < 16; ++e) {
                    int c = cgh * 160 + ct * 32 + (e & 3) + 8 * (e >> 2) + 4 * hi;
                    fb[(iw * 32 + r) * 328 + c] = f2b(o[ct][e] * fsc);
                }
        }
        __syncthreads();    // syncB
        if (pj == 0) {
            #pragma unroll
            for (int ct = 0; ct < 5; ++ct)
                #pragma unroll
                for (int g = 0; g < 4; ++g) {
                    int cb = cgh * 160 + ct * 32 + 8 * g + 4 * hi;
                    u16* fr = &fb[(iw * 32 + r) * 328 + cb];
                    float v0 = (o[ct][4 * g + 0] * fsc + b2f(fr[0])) * inv;
                    float v1 = (o[ct][4 * g + 1] * fsc + b2f(fr[1])) * inv;
                    float v2 = (o[ct][4 * g + 2] * fsc + b2f(fr[2])) * inv;
                    float v3 = (o[ct][4 * g + 3] * fsc + b2f(fr[3])) * inv;
                    *(unsigned*)(fr) = cvt_pk_bf16(v0, v1);
                    *(unsigned*)(fr + 2) = cvt_pk_bf16(v2, v3);
                }
        }
        __syncthreads();    // syncC
        #undef PV_BODY
        #undef STAGE
    }

    // ---- common: store AO (64 q-rows x 320 ch) from smem [64][328] ----
    const u16* ob = (const u16*)smem;
    u16* AOb = AO + ((size_t)b * NN + i0) * CU;
    #pragma unroll
    for (int n = 0; n < 3; ++n) {
        int id = n * 768 + t;
        int row = id / 40, c8 = id % 40;
        bf16x8 val = *(const bf16x8*)(ob + row * 328 + c8 * 8);
        *(bf16x8*)(AOb + (size_t)row * CU + c8 * 8) = val;
    }
    if (t < 256) {
        int id = 2304 + t;
        int row = id / 40, c8 = id % 40;
        bf16x8 val = *(const bf16x8*)(ob + row * 328 + c8 * 8);
        *(bf16x8*)(AOb + (size_t)row * CU + c8 * 8) = val;
    }
}

extern "C" void kernel_launch(void* const* d_in, const int* in_sizes, int n_in,
                              void* d_out, int out_size, void* d_ws, size_t ws_size,
                              hipStream_t stream) {
    const float* unet  = (const float*)d_in[0];
    const float* janus = (const float*)d_in[1];
    const float* Wq = (const float*)d_in[2];
    const float* bq = (const float*)d_in[3];
    const float* Wk = (const float*)d_in[4];
    const float* bk = (const float*)d_in[5];
    const float* Wv = (const float*)d_in[6];
    const float* bv = (const float*)d_in[7];
    const float* Wo = (const float*)d_in[8];
    const float* bo = (const float*)d_in[9];
    float* out = (float*)d_out;

    char* ws = (char*)d_ws;
    u16* Xu  = (u16*)(ws + XU_OFF);
    u16* Xj  = (u16*)(ws + XJ_OFF);
    u16* Qb  = (u16*)(ws + QB_OFF);
    u16* Kb  = (u16*)(ws + KB_OFF);
    u16* Vb  = (u16*)(ws + VB_OFF);
    u16* wq  = (u16*)(ws + WQ_OFF);
    u16* wk  = (u16*)(ws + WK_OFF);
    u16* wv  = (u16*)(ws + WV_OFF);
    u16* wo  = (u16*)(ws + WO_OFF);
    u16* AO  = (u16*)(ws + AO_OFF);

    // fused prep: transposes + weight cast
    prep_kernel<<<8400, 256, 0, stream>>>(unet, janus, Wq, Wk, Wv, Wo,
                                          Xu, Xj, wq, wk, wv, wo);

    // fused Q + K + V projections (all three run concurrently)
    gemm_qkv_kernel<<<dim3(64, 13), 512, 0, stream>>>(
        Xu, Xj, wq, wk, wv, bq, bk, bv, Qb, Kb, Vb);

    attn_kernel<<<256, 768, 0, stream>>>(Qb, Kb, Vb, AO);

    gemm_final_kernel<320, 320><<<dim3(64, 5), 512, 0, stream>>>(
        AO, wo, bo, out, unet);
}